// Round 6
// baseline (229.417 us; speedup 1.0000x reference)
//
#include <hip/hip_runtime.h>
#include <math.h>

#define NPB 256           // nodes per bucket
#define BSH 8
#define MAXNB 400
#define BIN_CHUNK 4096
#define HIST_CHUNK 4096

typedef __attribute__((ext_vector_type(8))) short bf16x8;
typedef __attribute__((ext_vector_type(4))) float f32x4;
typedef __attribute__((ext_vector_type(2))) float f32x2;

__device__ __forceinline__ unsigned short f2bf(float f){
  unsigned int u = __float_as_uint(f);
  unsigned int r = (u + 0x7FFFu + ((u >> 16) & 1u)) >> 16;   // RNE
  return (unsigned short)r;
}

// pack 8 f32 -> bf16x8 via v_cvt_pk_bf16_f32 (RNE, 1 inst / 2 floats)
__device__ __forceinline__ bf16x8 cvt8(float4 a, float4 b){
  union { unsigned u[4]; bf16x8 v; } r;
  asm("v_cvt_pk_bf16_f32 %0, %1, %2" : "=v"(r.u[0]) : "v"(a.x), "v"(a.y));
  asm("v_cvt_pk_bf16_f32 %0, %1, %2" : "=v"(r.u[1]) : "v"(a.z), "v"(a.w));
  asm("v_cvt_pk_bf16_f32 %0, %1, %2" : "=v"(r.u[2]) : "v"(b.x), "v"(b.y));
  asm("v_cvt_pk_bf16_f32 %0, %1, %2" : "=v"(r.u[3]) : "v"(b.z), "v"(b.w));
  return r.v;
}

// ---------------- CSR build (bucketed two-pass) + weight prep folded in ----------------

// blocks [0, NBH): edge histogram into NB bucket counters (chunk = HIST_CHUNK)
// block NBH:   W1 -> W1^T bf16
// block NBH+1: W2 -> W2^T bf16 (padded to 48 classes)
__global__ __launch_bounds__(256) void k_bhist(const int* __restrict__ dst, int E,
                                               int* __restrict__ bcnt, int NB, int NBH,
                                               const float* __restrict__ W1,
                                               const float* __restrict__ W2,
                                               unsigned short* __restrict__ w1t,
                                               unsigned short* __restrict__ w2t){
  __shared__ int l[MAXNB];
  int t = threadIdx.x, b = blockIdx.x;
  if(b >= NBH){
    if(b == NBH){
      for(int i = t; i < 8192; i += 256){
        int k = i >> 6, f = i & 63;
        w1t[f*128 + k] = f2bf(W1[i]);
      }
    } else {
      for(int i = t; i < 3072; i += 256){
        int c = i >> 6, k = i & 63;
        w2t[c*64 + k] = (c < 40) ? f2bf(W2[k*40 + c]) : (unsigned short)0;
      }
    }
    return;
  }
  int base = b*HIST_CHUNK;
  int end = base + HIST_CHUNK; if(end > E) end = E;
  for(int i = t; i < NB; i += 256) l[i] = 0;
  __syncthreads();
  for(int i = base + t; i < end; i += 256) atomicAdd(&l[dst[i] >> BSH], 1);
  __syncthreads();
  for(int i = t; i < NB; i += 256){ int c = l[i]; if(c) atomicAdd(&bcnt[i], c); }
}

__global__ void k_bscan(const int* __restrict__ bcnt, int* __restrict__ bofs,
                        int* __restrict__ bcur, int NB, int E){
  __shared__ int sh[1024];
  int t = threadIdx.x;
  int c0 = (2*t   < NB) ? bcnt[2*t]   : 0;
  int c1 = (2*t+1 < NB) ? bcnt[2*t+1] : 0;
  sh[t] = c0 + c1; __syncthreads();
  for(int off = 1; off < 1024; off <<= 1){
    int v = (t >= off) ? sh[t - off] : 0;
    __syncthreads();
    sh[t] += v;
    __syncthreads();
  }
  int pairEx = sh[t] - (c0 + c1);
  if(2*t   < NB){ bofs[2*t]   = pairEx;      bcur[2*t]   = pairEx; }
  if(2*t+1 < NB){ bofs[2*t+1] = pairEx + c0; bcur[2*t+1] = pairEx + c0; }
  if(t == 0) bofs[NB] = E;
}

__global__ __launch_bounds__(256) void k_binpass(const int* __restrict__ src,
                          const int* __restrict__ dst, int E,
                          int* __restrict__ bcur, unsigned int* __restrict__ binned, int NB){
  __shared__ int lcnt[MAXNB];
  __shared__ int lpos[MAXNB];
  int t = threadIdx.x;
  int base = blockIdx.x * BIN_CHUNK;
  int end = base + BIN_CHUNK; if(end > E) end = E;
  for(int b = t; b < NB; b += 256) lcnt[b] = 0;
  __syncthreads();
  for(int i = base + t; i < end; i += 256)
    atomicAdd(&lcnt[dst[i] >> BSH], 1);
  __syncthreads();
  for(int b = t; b < NB; b += 256){
    int c = lcnt[b];
    lpos[b] = c ? atomicAdd(&bcur[b], c) : 0;
  }
  __syncthreads();
  for(int i = base + t; i < end; i += 256){
    int d = dst[i];
    int b = d >> BSH;
    unsigned int rec = (unsigned int)src[i] | ((unsigned int)(d & (NPB-1)) << 17);
    int p = atomicAdd(&lpos[b], 1);
    binned[p] = rec;
  }
}

// one block per 256-node bucket: LDS hist + 4-wave scan -> row_ofs, dinv, csr
__global__ __launch_bounds__(256) void k_bscatter(const unsigned int* __restrict__ binned,
     const int* __restrict__ bofs, int* __restrict__ csr, int* __restrict__ row_ofs,
     float* __restrict__ dinv, int N, int E, int NB){
  __shared__ int lcnt[NPB];
  __shared__ int lofs[NPB];
  __shared__ int lcur[NPB];
  __shared__ int wsum[4];
  int b = blockIdx.x, t = threadIdx.x;
  int beg = bofs[b], end = bofs[b+1];
  lcnt[t] = 0;
  __syncthreads();
  for(int i = beg + t; i < end; i += 256) atomicAdd(&lcnt[binned[i] >> 17], 1);
  __syncthreads();
  int c = lcnt[t];
  int lane = t & 63, wid = t >> 6;
  int v = c;
  #pragma unroll
  for(int off = 1; off < 64; off <<= 1){
    int nv = __shfl_up(v, off, 64);
    if(lane >= off) v += nv;
  }
  if(lane == 63) wsum[wid] = v;
  __syncthreads();
  int wpre = 0;
  #pragma unroll
  for(int k2 = 0; k2 < 4; k2++) if(k2 < wid) wpre += wsum[k2];
  int ex = wpre + v - c;
  lofs[t] = beg + ex; lcur[t] = 0;
  int node = (b << BSH) + t;
  if(node < N){
    row_ofs[node] = beg + ex;
    dinv[node] = rsqrtf((float)(c + 1));   // +1 self loop
  }
  __syncthreads();
  for(int i = beg + t; i < end; i += 256){
    unsigned int rec = binned[i];
    int dl = rec >> 17;
    int pos = lofs[dl] + atomicAdd(&lcur[dl], 1);
    csr[pos] = (int)(rec & 0x1FFFFu);
  }
  if(b == NB-1 && t == 0) row_ofs[N] = E;
}

// ---------------- GEMM1 (MFMA bf16): g1 = fp8( dinv * (x @ W1) ) ----------------
__global__ __launch_bounds__(256) void k_gemm1(const float* __restrict__ x,
                        const unsigned short* __restrict__ w1t,
                        const float* __restrict__ dinv, unsigned int* __restrict__ g1, int n){
  __shared__ unsigned short xs[128*136];  // x tile bf16 [node][k]
  __shared__ unsigned short wt[64*136];   // W1^T bf16 [feat][k]
  int tid = threadIdx.x;
  int nodeBase = blockIdx.x*128;
  for(int i = tid; i < 1024; i += 256){
    int f = i >> 4, seg = i & 15;
    *(uint4*)&wt[f*136 + seg*8] = *(const uint4*)&w1t[f*128 + seg*8];
  }
  {
    const float4* x4 = (const float4*)x;
    for(int i = tid; i < 2048; i += 256){
      int node = i >> 4, seg = i & 15;     // 8 floats per chunk
      float4 va = make_float4(0.f,0.f,0.f,0.f), vb = va;
      if(nodeBase + node < n){
        va = x4[(size_t)(nodeBase + node)*32 + seg*2];
        vb = x4[(size_t)(nodeBase + node)*32 + seg*2 + 1];
      }
      *(bf16x8*)&xs[node*136 + seg*8] = cvt8(va, vb);
    }
  }
  __syncthreads();

  int w = tid >> 6, lane = tid & 63;
  int ml = lane & 15, q = lane >> 4;
  int n0 = nodeBase + w*32 + ml;
  int n1 = n0 + 16;
  bool vn0 = n0 < n, vn1 = n1 < n;

  f32x4 a00 = {0.f,0.f,0.f,0.f}, a01 = {0.f,0.f,0.f,0.f},
        a02 = {0.f,0.f,0.f,0.f}, a03 = {0.f,0.f,0.f,0.f};
  f32x4 a10 = {0.f,0.f,0.f,0.f}, a11 = {0.f,0.f,0.f,0.f},
        a12 = {0.f,0.f,0.f,0.f}, a13 = {0.f,0.f,0.f,0.f};
  const unsigned short* brow = &xs[(w*32 + ml)*136 + q*8];
  const unsigned short* arow = &wt[ml*136 + q*8];
  #pragma unroll
  for(int s = 0; s < 4; s++){
    bf16x8 bb0 = *(const bf16x8*)(brow +        s*32);
    bf16x8 bb1 = *(const bf16x8*)(brow + 2176 + s*32);   // +16*136
    bf16x8 a0 = *(const bf16x8*)(arow +    0 + s*32);
    bf16x8 a1 = *(const bf16x8*)(arow + 2176 + s*32);
    bf16x8 a2 = *(const bf16x8*)(arow + 4352 + s*32);
    bf16x8 a3 = *(const bf16x8*)(arow + 6528 + s*32);
    a00 = __builtin_amdgcn_mfma_f32_16x16x32_bf16(a0, bb0, a00, 0, 0, 0);
    a01 = __builtin_amdgcn_mfma_f32_16x16x32_bf16(a1, bb0, a01, 0, 0, 0);
    a02 = __builtin_amdgcn_mfma_f32_16x16x32_bf16(a2, bb0, a02, 0, 0, 0);
    a03 = __builtin_amdgcn_mfma_f32_16x16x32_bf16(a3, bb0, a03, 0, 0, 0);
    a10 = __builtin_amdgcn_mfma_f32_16x16x32_bf16(a0, bb1, a10, 0, 0, 0);
    a11 = __builtin_amdgcn_mfma_f32_16x16x32_bf16(a1, bb1, a11, 0, 0, 0);
    a12 = __builtin_amdgcn_mfma_f32_16x16x32_bf16(a2, bb1, a12, 0, 0, 0);
    a13 = __builtin_amdgcn_mfma_f32_16x16x32_bf16(a3, bb1, a13, 0, 0, 0);
  }
  if(vn0){
    float dv = dinv[n0];
    unsigned base16 = ((unsigned)n0 << 4) + q;
    int p;
    p = __builtin_amdgcn_cvt_pk_fp8_f32(a00[0]*dv, a00[1]*dv, 0, false);
    p = __builtin_amdgcn_cvt_pk_fp8_f32(a00[2]*dv, a00[3]*dv, p, true);
    g1[base16 +  0] = (unsigned)p;
    p = __builtin_amdgcn_cvt_pk_fp8_f32(a01[0]*dv, a01[1]*dv, 0, false);
    p = __builtin_amdgcn_cvt_pk_fp8_f32(a01[2]*dv, a01[3]*dv, p, true);
    g1[base16 +  4] = (unsigned)p;
    p = __builtin_amdgcn_cvt_pk_fp8_f32(a02[0]*dv, a02[1]*dv, 0, false);
    p = __builtin_amdgcn_cvt_pk_fp8_f32(a02[2]*dv, a02[3]*dv, p, true);
    g1[base16 +  8] = (unsigned)p;
    p = __builtin_amdgcn_cvt_pk_fp8_f32(a03[0]*dv, a03[1]*dv, 0, false);
    p = __builtin_amdgcn_cvt_pk_fp8_f32(a03[2]*dv, a03[3]*dv, p, true);
    g1[base16 + 12] = (unsigned)p;
  }
  if(vn1){
    float dv = dinv[n1];
    unsigned base16 = ((unsigned)n1 << 4) + q;
    int p;
    p = __builtin_amdgcn_cvt_pk_fp8_f32(a10[0]*dv, a10[1]*dv, 0, false);
    p = __builtin_amdgcn_cvt_pk_fp8_f32(a10[2]*dv, a10[3]*dv, p, true);
    g1[base16 +  0] = (unsigned)p;
    p = __builtin_amdgcn_cvt_pk_fp8_f32(a11[0]*dv, a11[1]*dv, 0, false);
    p = __builtin_amdgcn_cvt_pk_fp8_f32(a11[2]*dv, a11[3]*dv, p, true);
    g1[base16 +  4] = (unsigned)p;
    p = __builtin_amdgcn_cvt_pk_fp8_f32(a12[0]*dv, a12[1]*dv, 0, false);
    p = __builtin_amdgcn_cvt_pk_fp8_f32(a12[2]*dv, a12[3]*dv, p, true);
    g1[base16 +  8] = (unsigned)p;
    p = __builtin_amdgcn_cvt_pk_fp8_f32(a13[0]*dv, a13[1]*dv, 0, false);
    p = __builtin_amdgcn_cvt_pk_fp8_f32(a13[2]*dv, a13[3]*dv, p, true);
    g1[base16 + 12] = (unsigned)p;
  }
}

// ---------------- fused agg1 + gemm2 with intra-block work stealing ----------------
// 64 nodes/block. Quarters grab nodes via LDS ticket counter (balance), lane f
// owns feats 4f..4f+3; u-row -> LDS; then 6 MFMAs/wave -> fp8 g2 (40-B rows).
__global__ __launch_bounds__(256) void k_agg1g2(const unsigned* __restrict__ g1,
    const int* __restrict__ row_ofs, const int* __restrict__ csr,
    const float* __restrict__ dinv, const float* __restrict__ b1,
    const unsigned short* __restrict__ w2t, unsigned char* __restrict__ g2, int n){
  __shared__ unsigned short us[64*72];    // u tile bf16 [node][k]
  __shared__ unsigned short ws2[48*72];   // W2^T bf16 [class][k]
  __shared__ int nctr;
  int t = threadIdx.x;
  int nodeBase = blockIdx.x*64;
  for(int i = t; i < 384; i += 256){
    int row = i >> 3, seg = i & 7;
    *(uint4*)&ws2[row*72 + seg*8] = *(const uint4*)&w2t[row*64 + seg*8];
  }
  if(t == 0) nctr = 0;
  __syncthreads();
  int lane = t & 63;
  int lq = lane & 15;                     // f
  int qsrc = lane & 48;                   // quarter base lane
  int bq = qsrc << 2;                     // bpermute byte base
  float4 bb1 = ((const float4*)b1)[lq];
  int myi = -1;                           // -1 need node, -2 done, else local row
  int e = 0, eend = 0;
  float dv = 0.f;
  f32x2 s01 = {0.f,0.f}, s23 = {0.f,0.f};
  for(;;){
    if(myi == -1){
      int tk = 0;
      if(lq == 0) tk = atomicAdd(&nctr, 1);
      tk = __shfl(tk, qsrc, 64);
      if(tk >= 64){ myi = -2; }
      else {
        myi = tk;
        int node = nodeBase + tk;
        if(node < n){
          e = row_ofs[node]; eend = row_ofs[node+1];
          dv = dinv[node];
          unsigned v = g1[((unsigned)node << 4) + lq];   // self row (once)
          s01 = __builtin_amdgcn_cvt_pk_f32_fp8(v, false);
          s23 = __builtin_amdgcn_cvt_pk_f32_fp8(v, true);
        } else {
          e = 0; eend = 0; dv = 0.f;
          s01 = (f32x2){0.f,0.f}; s23 = (f32x2){0.f,0.f};
        }
      }
    }
    if(__all(myi == -2)) break;
    if(myi >= 0){
      int rem = eend - e; if(rem > 16) rem = 16;
      if(rem > 0){
        int idxv = (lq < rem) ? csr[e + lq] : 0;
        int j = 0;
        for(; j + 4 <= rem; j += 4){
          int r0 = __builtin_amdgcn_ds_bpermute(bq + ((j+0) << 2), idxv);
          int r1 = __builtin_amdgcn_ds_bpermute(bq + ((j+1) << 2), idxv);
          int r2 = __builtin_amdgcn_ds_bpermute(bq + ((j+2) << 2), idxv);
          int r3 = __builtin_amdgcn_ds_bpermute(bq + ((j+3) << 2), idxv);
          unsigned v0 = g1[((unsigned)r0 << 4) + lq];
          unsigned v1 = g1[((unsigned)r1 << 4) + lq];
          unsigned v2 = g1[((unsigned)r2 << 4) + lq];
          unsigned v3 = g1[((unsigned)r3 << 4) + lq];
          s01 += __builtin_amdgcn_cvt_pk_f32_fp8(v0, false);
          s23 += __builtin_amdgcn_cvt_pk_f32_fp8(v0, true);
          s01 += __builtin_amdgcn_cvt_pk_f32_fp8(v1, false);
          s23 += __builtin_amdgcn_cvt_pk_f32_fp8(v1, true);
          s01 += __builtin_amdgcn_cvt_pk_f32_fp8(v2, false);
          s23 += __builtin_amdgcn_cvt_pk_f32_fp8(v2, true);
          s01 += __builtin_amdgcn_cvt_pk_f32_fp8(v3, false);
          s23 += __builtin_amdgcn_cvt_pk_f32_fp8(v3, true);
        }
        for(; j < rem; j++){
          int r0 = __builtin_amdgcn_ds_bpermute(bq + (j << 2), idxv);
          unsigned v0 = g1[((unsigned)r0 << 4) + lq];
          s01 += __builtin_amdgcn_cvt_pk_f32_fp8(v0, false);
          s23 += __builtin_amdgcn_cvt_pk_f32_fp8(v0, true);
        }
        e += rem;
      }
      if(e >= eend){
        float h0 = fmaxf(fmaf(dv, s01.x, bb1.x), 0.f);
        float h1 = fmaxf(fmaf(dv, s01.y, bb1.y), 0.f);
        float h2 = fmaxf(fmaf(dv, s23.x, bb1.z), 0.f);
        float h3 = fmaxf(fmaf(dv, s23.y, bb1.w), 0.f);
        unsigned p0, p1;
        asm("v_cvt_pk_bf16_f32 %0, %1, %2" : "=v"(p0) : "v"(dv*h0), "v"(dv*h1));
        asm("v_cvt_pk_bf16_f32 %0, %1, %2" : "=v"(p1) : "v"(dv*h2), "v"(dv*h3));
        *(uint2*)&us[myi*72 + lq*4] = make_uint2(p0, p1);
        myi = -1;
      }
    }
  }
  __syncthreads();
  // ---- MFMA phase (classes padded to 48) ----
  int w = t >> 6;
  int ml = lane & 15, q = lane >> 4;
  f32x4 acc0 = {0.f,0.f,0.f,0.f}, acc1 = {0.f,0.f,0.f,0.f}, acc2 = {0.f,0.f,0.f,0.f};
  const unsigned short* brow = &us[(w*16 + ml)*72 + q*8];
  const unsigned short* a0r = &ws2[ml*72 + q*8];
  #pragma unroll
  for(int s = 0; s < 2; s++){
    bf16x8 bb = *(const bf16x8*)(brow + s*32);
    bf16x8 a0 = *(const bf16x8*)(a0r +    0 + s*32);
    bf16x8 a1 = *(const bf16x8*)(a0r + 1152 + s*32);   // +16*72
    bf16x8 a2 = *(const bf16x8*)(a0r + 2304 + s*32);   // +32*72
    acc0 = __builtin_amdgcn_mfma_f32_16x16x32_bf16(a0, bb, acc0, 0, 0, 0);
    acc1 = __builtin_amdgcn_mfma_f32_16x16x32_bf16(a1, bb, acc1, 0, 0, 0);
    acc2 = __builtin_amdgcn_mfma_f32_16x16x32_bf16(a2, bb, acc2, 0, 0, 0);
  }
  // D: col = node (ml), row = class = ctile*16 + q*4 + r -> row dword = ctile*4 + q
  int node = nodeBase + w*16 + ml;
  if(node < n){
    unsigned* gd = (unsigned*)g2;
    unsigned rb = (unsigned)node*10u + q;
    int p;
    p = __builtin_amdgcn_cvt_pk_fp8_f32(acc0[0], acc0[1], 0, false);
    p = __builtin_amdgcn_cvt_pk_fp8_f32(acc0[2], acc0[3], p, true);
    gd[rb + 0] = (unsigned)p;
    p = __builtin_amdgcn_cvt_pk_fp8_f32(acc1[0], acc1[1], 0, false);
    p = __builtin_amdgcn_cvt_pk_fp8_f32(acc1[2], acc1[3], p, true);
    gd[rb + 4] = (unsigned)p;
    if(q < 2){
      p = __builtin_amdgcn_cvt_pk_fp8_f32(acc2[0], acc2[1], 0, false);
      p = __builtin_amdgcn_cvt_pk_fp8_f32(acc2[2], acc2[3], p, true);
      gd[rb + 8] = (unsigned)p;
    }
  }
}

// ---------------- agg2 with work stealing: gather + bias + log_softmax ----------------
// 64 nodes/block, quarters grab nodes via LDS ticket counter.
__global__ __launch_bounds__(256) void k_agg2(const unsigned char* __restrict__ g2,
     const int* __restrict__ row_ofs, const int* __restrict__ csr,
     const float* __restrict__ dinv, const float* __restrict__ b2,
     float* __restrict__ out, int N){
  __shared__ int nctr;
  int t = threadIdx.x;
  if(t == 0) nctr = 0;
  __syncthreads();
  int lane = t & 63;
  int lq = lane & 15;
  int fc = (lq < 10) ? lq : 0;            // lanes >=10 duplicate dword0, discarded
  int qsrc = lane & 48;
  int bq = qsrc << 2;
  int nodeBase = blockIdx.x*64;
  const unsigned* gd = (const unsigned*)g2;   // row = 10 dwords (40 fp8)
  float4 bb2 = ((const float4*)b2)[fc];
  int myi = -1;
  int e = 0, eend = 0;
  float dv = 0.f;
  f32x2 s01 = {0.f,0.f}, s23 = {0.f,0.f};
  for(;;){
    if(myi == -1){
      int tk = 0;
      if(lq == 0) tk = atomicAdd(&nctr, 1);
      tk = __shfl(tk, qsrc, 64);
      if(tk >= 64){ myi = -2; }
      else {
        myi = tk;
        int node = nodeBase + tk;
        if(node < N){
          e = row_ofs[node]; eend = row_ofs[node+1];
          dv = dinv[node];
          unsigned v = gd[(unsigned)node*10u + fc];     // self row
          s01 = __builtin_amdgcn_cvt_pk_f32_fp8(v, false);
          s23 = __builtin_amdgcn_cvt_pk_f32_fp8(v, true);
        } else {
          e = 0; eend = 0; dv = 0.f;
          s01 = (f32x2){0.f,0.f}; s23 = (f32x2){0.f,0.f};
        }
      }
    }
    if(__all(myi == -2)) break;
    if(myi >= 0){
      int rem = eend - e; if(rem > 16) rem = 16;
      if(rem > 0){
        int idxv = (lq < rem) ? csr[e + lq] : 0;
        int j = 0;
        for(; j + 4 <= rem; j += 4){
          int r0 = __builtin_amdgcn_ds_bpermute(bq + ((j+0) << 2), idxv);
          int r1 = __builtin_amdgcn_ds_bpermute(bq + ((j+1) << 2), idxv);
          int r2 = __builtin_amdgcn_ds_bpermute(bq + ((j+2) << 2), idxv);
          int r3 = __builtin_amdgcn_ds_bpermute(bq + ((j+3) << 2), idxv);
          unsigned v0 = gd[(unsigned)r0*10u + fc];
          unsigned v1 = gd[(unsigned)r1*10u + fc];
          unsigned v2 = gd[(unsigned)r2*10u + fc];
          unsigned v3 = gd[(unsigned)r3*10u + fc];
          s01 += __builtin_amdgcn_cvt_pk_f32_fp8(v0, false);
          s23 += __builtin_amdgcn_cvt_pk_f32_fp8(v0, true);
          s01 += __builtin_amdgcn_cvt_pk_f32_fp8(v1, false);
          s23 += __builtin_amdgcn_cvt_pk_f32_fp8(v1, true);
          s01 += __builtin_amdgcn_cvt_pk_f32_fp8(v2, false);
          s23 += __builtin_amdgcn_cvt_pk_f32_fp8(v2, true);
          s01 += __builtin_amdgcn_cvt_pk_f32_fp8(v3, false);
          s23 += __builtin_amdgcn_cvt_pk_f32_fp8(v3, true);
        }
        for(; j < rem; j++){
          int r0 = __builtin_amdgcn_ds_bpermute(bq + (j << 2), idxv);
          unsigned v0 = gd[(unsigned)r0*10u + fc];
          s01 += __builtin_amdgcn_cvt_pk_f32_fp8(v0, false);
          s23 += __builtin_amdgcn_cvt_pk_f32_fp8(v0, true);
        }
        e += rem;
      }
      if(e >= eend){
        int node = nodeBase + myi;
        if(node < N){
          float l0 = fmaf(dv, s01.x, bb2.x);
          float l1 = fmaf(dv, s01.y, bb2.y);
          float l2 = fmaf(dv, s23.x, bb2.z);
          float l3 = fmaf(dv, s23.y, bb2.w);
          bool valid = (lq < 10);
          float m = valid ? fmaxf(fmaxf(l0,l1), fmaxf(l2,l3)) : -INFINITY;
          m = fmaxf(m, __shfl_xor(m,1,64)); m = fmaxf(m, __shfl_xor(m,2,64));
          m = fmaxf(m, __shfl_xor(m,4,64)); m = fmaxf(m, __shfl_xor(m,8,64));
          float ex = valid ? (expf(l0-m)+expf(l1-m)) + (expf(l2-m)+expf(l3-m)) : 0.f;
          ex += __shfl_xor(ex,1,64); ex += __shfl_xor(ex,2,64);
          ex += __shfl_xor(ex,4,64); ex += __shfl_xor(ex,8,64);
          float ll = logf(ex);
          if(valid){
            ((float4*)out)[(unsigned)node*10u + lq] = make_float4(l0-m-ll, l1-m-ll, l2-m-ll, l3-m-ll);
          }
        }
        myi = -1;
      }
    }
  }
}

// ---------------- launch ----------------

extern "C" void kernel_launch(void* const* d_in, const int* in_sizes, int n_in,
                              void* d_out, int out_size, void* d_ws, size_t ws_size,
                              hipStream_t stream){
  const float* x  = (const float*)d_in[0];
  const int*   ei = (const int*)  d_in[1];
  const float* W1 = (const float*)d_in[2];
  const float* b1 = (const float*)d_in[3];
  const float* W2 = (const float*)d_in[4];
  const float* b2 = (const float*)d_in[5];
  float* out = (float*)d_out;

  int N = in_sizes[0] / 128;        // 100000
  int E = in_sizes[1] / 2;          // 1600000
  const int* src = ei;
  const int* dst = ei + E;
  int NB = (N + NPB - 1) >> BSH;    // 391

  char* w = (char*)d_ws;
  auto alloc = [&](size_t bytes) -> char* {
    char* p = w;
    w += (bytes + 511) & ~(size_t)511;
    return p;
  };
  int*   bcnt    = (int*)  alloc((size_t)NB*4);
  int*   bofs    = (int*)  alloc((size_t)(NB+1)*4);
  int*   bcur    = (int*)  alloc((size_t)NB*4);
  int*   row_ofs = (int*)  alloc((size_t)(N+1)*4);
  float* dinv    = (float*)alloc((size_t)N*4);
  unsigned int* binned = (unsigned int*)alloc((size_t)E*4);
  int*   csr     = (int*)  alloc((size_t)E*4);
  unsigned int*   g1 = (unsigned int*)  alloc((size_t)N*64);   // fp8, 64 B rows
  unsigned char*  g2 = (unsigned char*) alloc((size_t)N*40);   // fp8, 40 B rows
  unsigned short* w1t = (unsigned short*)alloc((size_t)64*128*2); // W1^T bf16
  unsigned short* w2t = (unsigned short*)alloc((size_t)48*64*2);  // W2^T bf16 (padded)

  int NBH = (E + HIST_CHUNK - 1)/HIST_CHUNK;   // 391 hist blocks

  hipMemsetAsync(bcnt, 0, (size_t)NB*4, stream);
  k_bhist   <<<NBH+2, 256, 0, stream>>>(dst, E, bcnt, NB, NBH, W1, W2, w1t, w2t);
  k_bscan   <<<1, 1024, 0, stream>>>(bcnt, bofs, bcur, NB, E);
  k_binpass <<<(E+BIN_CHUNK-1)/BIN_CHUNK, 256, 0, stream>>>(src, dst, E, bcur, binned, NB);
  k_bscatter<<<NB, 256, 0, stream>>>(binned, bofs, csr, row_ofs, dinv, N, E, NB);

  k_gemm1   <<<(N+127)/128, 256, 0, stream>>>(x, w1t, dinv, g1, N);
  k_agg1g2  <<<(N+63)/64, 256, 0, stream>>>(g1, row_ofs, csr, dinv, b1, w2t, g2, N);
  k_agg2    <<<(N+63)/64, 256, 0, stream>>>(g2, row_ofs, csr, dinv, b2, out, N);
}

// Round 7
// 219.108 us; speedup vs baseline: 1.0471x; 1.0471x over previous
//
#include <hip/hip_runtime.h>
#include <math.h>

#define NPB 256           // nodes per bucket
#define BSH 8
#define MAXNB 400
#define BIN_CHUNK 4096
#define HIST_CHUNK 4096

typedef __attribute__((ext_vector_type(8))) short bf16x8;
typedef __attribute__((ext_vector_type(4))) float f32x4;
typedef __attribute__((ext_vector_type(2))) float f32x2;

__device__ __forceinline__ unsigned short f2bf(float f){
  unsigned int u = __float_as_uint(f);
  unsigned int r = (u + 0x7FFFu + ((u >> 16) & 1u)) >> 16;   // RNE
  return (unsigned short)r;
}

// pack 8 f32 -> bf16x8 via v_cvt_pk_bf16_f32 (RNE, 1 inst / 2 floats)
__device__ __forceinline__ bf16x8 cvt8(float4 a, float4 b){
  union { unsigned u[4]; bf16x8 v; } r;
  asm("v_cvt_pk_bf16_f32 %0, %1, %2" : "=v"(r.u[0]) : "v"(a.x), "v"(a.y));
  asm("v_cvt_pk_bf16_f32 %0, %1, %2" : "=v"(r.u[1]) : "v"(a.z), "v"(a.w));
  asm("v_cvt_pk_bf16_f32 %0, %1, %2" : "=v"(r.u[2]) : "v"(b.x), "v"(b.y));
  asm("v_cvt_pk_bf16_f32 %0, %1, %2" : "=v"(r.u[3]) : "v"(b.z), "v"(b.w));
  return r.v;
}

// ---------------- CSR build (bucketed two-pass) + weight prep folded in ----------------

__global__ __launch_bounds__(256) void k_bhist(const int* __restrict__ dst, int E,
                                               int* __restrict__ bcnt, int NB, int NBH,
                                               const float* __restrict__ W1,
                                               const float* __restrict__ W2,
                                               unsigned short* __restrict__ w1t,
                                               unsigned short* __restrict__ w2t){
  __shared__ int l[MAXNB];
  int t = threadIdx.x, b = blockIdx.x;
  if(b >= NBH){
    if(b == NBH){
      for(int i = t; i < 8192; i += 256){
        int k = i >> 6, f = i & 63;
        w1t[f*128 + k] = f2bf(W1[i]);
      }
    } else {
      for(int i = t; i < 3072; i += 256){
        int c = i >> 6, k = i & 63;
        w2t[c*64 + k] = (c < 40) ? f2bf(W2[k*40 + c]) : (unsigned short)0;
      }
    }
    return;
  }
  int base = b*HIST_CHUNK;
  int end = base + HIST_CHUNK; if(end > E) end = E;
  for(int i = t; i < NB; i += 256) l[i] = 0;
  __syncthreads();
  for(int i = base + t; i < end; i += 256) atomicAdd(&l[dst[i] >> BSH], 1);
  __syncthreads();
  for(int i = t; i < NB; i += 256){ int c = l[i]; if(c) atomicAdd(&bcnt[i], c); }
}

__global__ void k_bscan(const int* __restrict__ bcnt, int* __restrict__ bofs,
                        int* __restrict__ bcur, int NB, int E){
  __shared__ int sh[1024];
  int t = threadIdx.x;
  int c0 = (2*t   < NB) ? bcnt[2*t]   : 0;
  int c1 = (2*t+1 < NB) ? bcnt[2*t+1] : 0;
  sh[t] = c0 + c1; __syncthreads();
  for(int off = 1; off < 1024; off <<= 1){
    int v = (t >= off) ? sh[t - off] : 0;
    __syncthreads();
    sh[t] += v;
    __syncthreads();
  }
  int pairEx = sh[t] - (c0 + c1);
  if(2*t   < NB){ bofs[2*t]   = pairEx;      bcur[2*t]   = pairEx; }
  if(2*t+1 < NB){ bofs[2*t+1] = pairEx + c0; bcur[2*t+1] = pairEx + c0; }
  if(t == 0) bofs[NB] = E;
}

__global__ __launch_bounds__(256) void k_binpass(const int* __restrict__ src,
                          const int* __restrict__ dst, int E,
                          int* __restrict__ bcur, unsigned int* __restrict__ binned, int NB){
  __shared__ int lcnt[MAXNB];
  __shared__ int lpos[MAXNB];
  int t = threadIdx.x;
  int base = blockIdx.x * BIN_CHUNK;
  int end = base + BIN_CHUNK; if(end > E) end = E;
  for(int b = t; b < NB; b += 256) lcnt[b] = 0;
  __syncthreads();
  for(int i = base + t; i < end; i += 256)
    atomicAdd(&lcnt[dst[i] >> BSH], 1);
  __syncthreads();
  for(int b = t; b < NB; b += 256){
    int c = lcnt[b];
    lpos[b] = c ? atomicAdd(&bcur[b], c) : 0;
  }
  __syncthreads();
  for(int i = base + t; i < end; i += 256){
    int d = dst[i];
    int b = d >> BSH;
    unsigned int rec = (unsigned int)src[i] | ((unsigned int)(d & (NPB-1)) << 17);
    int p = atomicAdd(&lpos[b], 1);
    binned[p] = rec;
  }
}

// one block per 256-node bucket: LDS hist + 4-wave scan -> row_ofs, dinv, csr
__global__ __launch_bounds__(256) void k_bscatter(const unsigned int* __restrict__ binned,
     const int* __restrict__ bofs, int* __restrict__ csr, int* __restrict__ row_ofs,
     float* __restrict__ dinv, int N, int E, int NB){
  __shared__ int lcnt[NPB];
  __shared__ int lofs[NPB];
  __shared__ int lcur[NPB];
  __shared__ int wsum[4];
  int b = blockIdx.x, t = threadIdx.x;
  int beg = bofs[b], end = bofs[b+1];
  lcnt[t] = 0;
  __syncthreads();
  for(int i = beg + t; i < end; i += 256) atomicAdd(&lcnt[binned[i] >> 17], 1);
  __syncthreads();
  int c = lcnt[t];
  int lane = t & 63, wid = t >> 6;
  int v = c;
  #pragma unroll
  for(int off = 1; off < 64; off <<= 1){
    int nv = __shfl_up(v, off, 64);
    if(lane >= off) v += nv;
  }
  if(lane == 63) wsum[wid] = v;
  __syncthreads();
  int wpre = 0;
  #pragma unroll
  for(int k2 = 0; k2 < 4; k2++) if(k2 < wid) wpre += wsum[k2];
  int ex = wpre + v - c;
  lofs[t] = beg + ex; lcur[t] = 0;
  int node = (b << BSH) + t;
  if(node < N){
    row_ofs[node] = beg + ex;
    dinv[node] = rsqrtf((float)(c + 1));   // +1 self loop
  }
  __syncthreads();
  for(int i = beg + t; i < end; i += 256){
    unsigned int rec = binned[i];
    int dl = rec >> 17;
    int pos = lofs[dl] + atomicAdd(&lcur[dl], 1);
    csr[pos] = (int)(rec & 0x1FFFFu);
  }
  if(b == NB-1 && t == 0) row_ofs[N] = E;
}

// ---------------- GEMM1 (MFMA bf16): g1 = fp8( dinv * (x @ W1) ) ----------------
__global__ __launch_bounds__(256) void k_gemm1(const float* __restrict__ x,
                        const unsigned short* __restrict__ w1t,
                        const float* __restrict__ dinv, unsigned int* __restrict__ g1, int n){
  __shared__ unsigned short xs[128*136];  // x tile bf16 [node][k]
  __shared__ unsigned short wt[64*136];   // W1^T bf16 [feat][k]
  int tid = threadIdx.x;
  int nodeBase = blockIdx.x*128;
  for(int i = tid; i < 1024; i += 256){
    int f = i >> 4, seg = i & 15;
    *(uint4*)&wt[f*136 + seg*8] = *(const uint4*)&w1t[f*128 + seg*8];
  }
  {
    const float4* x4 = (const float4*)x;
    for(int i = tid; i < 2048; i += 256){
      int node = i >> 4, seg = i & 15;     // 8 floats per chunk
      float4 va = make_float4(0.f,0.f,0.f,0.f), vb = va;
      if(nodeBase + node < n){
        va = x4[(size_t)(nodeBase + node)*32 + seg*2];
        vb = x4[(size_t)(nodeBase + node)*32 + seg*2 + 1];
      }
      *(bf16x8*)&xs[node*136 + seg*8] = cvt8(va, vb);
    }
  }
  __syncthreads();

  int w = tid >> 6, lane = tid & 63;
  int ml = lane & 15, q = lane >> 4;
  int n0 = nodeBase + w*32 + ml;
  int n1 = n0 + 16;
  bool vn0 = n0 < n, vn1 = n1 < n;

  f32x4 a00 = {0.f,0.f,0.f,0.f}, a01 = {0.f,0.f,0.f,0.f},
        a02 = {0.f,0.f,0.f,0.f}, a03 = {0.f,0.f,0.f,0.f};
  f32x4 a10 = {0.f,0.f,0.f,0.f}, a11 = {0.f,0.f,0.f,0.f},
        a12 = {0.f,0.f,0.f,0.f}, a13 = {0.f,0.f,0.f,0.f};
  const unsigned short* brow = &xs[(w*32 + ml)*136 + q*8];
  const unsigned short* arow = &wt[ml*136 + q*8];
  #pragma unroll
  for(int s = 0; s < 4; s++){
    bf16x8 bb0 = *(const bf16x8*)(brow +        s*32);
    bf16x8 bb1 = *(const bf16x8*)(brow + 2176 + s*32);   // +16*136
    bf16x8 a0 = *(const bf16x8*)(arow +    0 + s*32);
    bf16x8 a1 = *(const bf16x8*)(arow + 2176 + s*32);
    bf16x8 a2 = *(const bf16x8*)(arow + 4352 + s*32);
    bf16x8 a3 = *(const bf16x8*)(arow + 6528 + s*32);
    a00 = __builtin_amdgcn_mfma_f32_16x16x32_bf16(a0, bb0, a00, 0, 0, 0);
    a01 = __builtin_amdgcn_mfma_f32_16x16x32_bf16(a1, bb0, a01, 0, 0, 0);
    a02 = __builtin_amdgcn_mfma_f32_16x16x32_bf16(a2, bb0, a02, 0, 0, 0);
    a03 = __builtin_amdgcn_mfma_f32_16x16x32_bf16(a3, bb0, a03, 0, 0, 0);
    a10 = __builtin_amdgcn_mfma_f32_16x16x32_bf16(a0, bb1, a10, 0, 0, 0);
    a11 = __builtin_amdgcn_mfma_f32_16x16x32_bf16(a1, bb1, a11, 0, 0, 0);
    a12 = __builtin_amdgcn_mfma_f32_16x16x32_bf16(a2, bb1, a12, 0, 0, 0);
    a13 = __builtin_amdgcn_mfma_f32_16x16x32_bf16(a3, bb1, a13, 0, 0, 0);
  }
  if(vn0){
    float dv = dinv[n0];
    unsigned base16 = ((unsigned)n0 << 4) + q;
    int p;
    p = __builtin_amdgcn_cvt_pk_fp8_f32(a00[0]*dv, a00[1]*dv, 0, false);
    p = __builtin_amdgcn_cvt_pk_fp8_f32(a00[2]*dv, a00[3]*dv, p, true);
    g1[base16 +  0] = (unsigned)p;
    p = __builtin_amdgcn_cvt_pk_fp8_f32(a01[0]*dv, a01[1]*dv, 0, false);
    p = __builtin_amdgcn_cvt_pk_fp8_f32(a01[2]*dv, a01[3]*dv, p, true);
    g1[base16 +  4] = (unsigned)p;
    p = __builtin_amdgcn_cvt_pk_fp8_f32(a02[0]*dv, a02[1]*dv, 0, false);
    p = __builtin_amdgcn_cvt_pk_fp8_f32(a02[2]*dv, a02[3]*dv, p, true);
    g1[base16 +  8] = (unsigned)p;
    p = __builtin_amdgcn_cvt_pk_fp8_f32(a03[0]*dv, a03[1]*dv, 0, false);
    p = __builtin_amdgcn_cvt_pk_fp8_f32(a03[2]*dv, a03[3]*dv, p, true);
    g1[base16 + 12] = (unsigned)p;
  }
  if(vn1){
    float dv = dinv[n1];
    unsigned base16 = ((unsigned)n1 << 4) + q;
    int p;
    p = __builtin_amdgcn_cvt_pk_fp8_f32(a10[0]*dv, a10[1]*dv, 0, false);
    p = __builtin_amdgcn_cvt_pk_fp8_f32(a10[2]*dv, a10[3]*dv, p, true);
    g1[base16 +  0] = (unsigned)p;
    p = __builtin_amdgcn_cvt_pk_fp8_f32(a11[0]*dv, a11[1]*dv, 0, false);
    p = __builtin_amdgcn_cvt_pk_fp8_f32(a11[2]*dv, a11[3]*dv, p, true);
    g1[base16 +  4] = (unsigned)p;
    p = __builtin_amdgcn_cvt_pk_fp8_f32(a12[0]*dv, a12[1]*dv, 0, false);
    p = __builtin_amdgcn_cvt_pk_fp8_f32(a12[2]*dv, a12[3]*dv, p, true);
    g1[base16 +  8] = (unsigned)p;
    p = __builtin_amdgcn_cvt_pk_fp8_f32(a13[0]*dv, a13[1]*dv, 0, false);
    p = __builtin_amdgcn_cvt_pk_fp8_f32(a13[2]*dv, a13[3]*dv, p, true);
    g1[base16 + 12] = (unsigned)p;
  }
}

// ---------------- fused agg1 + gemm2 (static quarters, 16-deep gather pipeline) ----------------
// 64 nodes/block. Each 16-lane quarter gathers 4 nodes serially; lane f owns
// feats 4f..4f+3. Full 16-edge chunks: 16 bpermutes -> 16 loads in flight ->
// accumulate. Then 6 MFMAs/wave (classes padded to 48) -> fp8 g2 (40-B rows).
__global__ __launch_bounds__(256) void k_agg1g2(const unsigned* __restrict__ g1,
    const int* __restrict__ row_ofs, const int* __restrict__ csr,
    const float* __restrict__ dinv, const float* __restrict__ b1,
    const unsigned short* __restrict__ w2t, unsigned char* __restrict__ g2, int n){
  __shared__ unsigned short us[64*72];    // u tile bf16 [node][k]
  __shared__ unsigned short ws2[48*72];   // W2^T bf16 [class][k]
  int t = threadIdx.x;
  int nodeBase = blockIdx.x*64;
  for(int i = t; i < 384; i += 256){
    int row = i >> 3, seg = i & 7;
    *(uint4*)&ws2[row*72 + seg*8] = *(const uint4*)&w2t[row*64 + seg*8];
  }
  int lane = t & 63;
  int f = lane & 15;
  int bq = (lane & 48) << 2;              // bpermute byte-addr base of own quarter
  int qg = t >> 4;                        // quarter index in block, 0..15
  float4 bb1 = ((const float4*)b1)[f];
  #pragma unroll 1
  for(int i = 0; i < 4; i++){
    int node = nodeBase + qg*4 + i;
    int lrow = qg*4 + i;
    if(node < n){
      int beg = row_ofs[node], end = row_ofs[node+1];
      unsigned v = g1[((unsigned)node << 4) + f];        // self row (once)
      f32x2 s01 = __builtin_amdgcn_cvt_pk_f32_fp8(v, false);
      f32x2 s23 = __builtin_amdgcn_cvt_pk_f32_fp8(v, true);
      for(int e = beg; e < end; e += 16){
        int rem = end - e; if(rem > 16) rem = 16;
        int idxv = (f < rem) ? csr[e + f] : 0;
        if(rem == 16){
          int r0,r1,r2,r3,r4,r5,r6,r7,r8,r9,r10,r11,r12,r13,r14,r15;
          r0  = __builtin_amdgcn_ds_bpermute(bq +  0, idxv);
          r1  = __builtin_amdgcn_ds_bpermute(bq +  4, idxv);
          r2  = __builtin_amdgcn_ds_bpermute(bq +  8, idxv);
          r3  = __builtin_amdgcn_ds_bpermute(bq + 12, idxv);
          r4  = __builtin_amdgcn_ds_bpermute(bq + 16, idxv);
          r5  = __builtin_amdgcn_ds_bpermute(bq + 20, idxv);
          r6  = __builtin_amdgcn_ds_bpermute(bq + 24, idxv);
          r7  = __builtin_amdgcn_ds_bpermute(bq + 28, idxv);
          r8  = __builtin_amdgcn_ds_bpermute(bq + 32, idxv);
          r9  = __builtin_amdgcn_ds_bpermute(bq + 36, idxv);
          r10 = __builtin_amdgcn_ds_bpermute(bq + 40, idxv);
          r11 = __builtin_amdgcn_ds_bpermute(bq + 44, idxv);
          r12 = __builtin_amdgcn_ds_bpermute(bq + 48, idxv);
          r13 = __builtin_amdgcn_ds_bpermute(bq + 52, idxv);
          r14 = __builtin_amdgcn_ds_bpermute(bq + 56, idxv);
          r15 = __builtin_amdgcn_ds_bpermute(bq + 60, idxv);
          unsigned w0  = g1[((unsigned)r0  << 4) + f];
          unsigned w1  = g1[((unsigned)r1  << 4) + f];
          unsigned w2  = g1[((unsigned)r2  << 4) + f];
          unsigned w3  = g1[((unsigned)r3  << 4) + f];
          unsigned w4  = g1[((unsigned)r4  << 4) + f];
          unsigned w5  = g1[((unsigned)r5  << 4) + f];
          unsigned w6  = g1[((unsigned)r6  << 4) + f];
          unsigned w7  = g1[((unsigned)r7  << 4) + f];
          unsigned w8  = g1[((unsigned)r8  << 4) + f];
          unsigned w9  = g1[((unsigned)r9  << 4) + f];
          unsigned w10 = g1[((unsigned)r10 << 4) + f];
          unsigned w11 = g1[((unsigned)r11 << 4) + f];
          unsigned w12 = g1[((unsigned)r12 << 4) + f];
          unsigned w13 = g1[((unsigned)r13 << 4) + f];
          unsigned w14 = g1[((unsigned)r14 << 4) + f];
          unsigned w15 = g1[((unsigned)r15 << 4) + f];
          s01 += __builtin_amdgcn_cvt_pk_f32_fp8(w0 , false); s23 += __builtin_amdgcn_cvt_pk_f32_fp8(w0 , true);
          s01 += __builtin_amdgcn_cvt_pk_f32_fp8(w1 , false); s23 += __builtin_amdgcn_cvt_pk_f32_fp8(w1 , true);
          s01 += __builtin_amdgcn_cvt_pk_f32_fp8(w2 , false); s23 += __builtin_amdgcn_cvt_pk_f32_fp8(w2 , true);
          s01 += __builtin_amdgcn_cvt_pk_f32_fp8(w3 , false); s23 += __builtin_amdgcn_cvt_pk_f32_fp8(w3 , true);
          s01 += __builtin_amdgcn_cvt_pk_f32_fp8(w4 , false); s23 += __builtin_amdgcn_cvt_pk_f32_fp8(w4 , true);
          s01 += __builtin_amdgcn_cvt_pk_f32_fp8(w5 , false); s23 += __builtin_amdgcn_cvt_pk_f32_fp8(w5 , true);
          s01 += __builtin_amdgcn_cvt_pk_f32_fp8(w6 , false); s23 += __builtin_amdgcn_cvt_pk_f32_fp8(w6 , true);
          s01 += __builtin_amdgcn_cvt_pk_f32_fp8(w7 , false); s23 += __builtin_amdgcn_cvt_pk_f32_fp8(w7 , true);
          s01 += __builtin_amdgcn_cvt_pk_f32_fp8(w8 , false); s23 += __builtin_amdgcn_cvt_pk_f32_fp8(w8 , true);
          s01 += __builtin_amdgcn_cvt_pk_f32_fp8(w9 , false); s23 += __builtin_amdgcn_cvt_pk_f32_fp8(w9 , true);
          s01 += __builtin_amdgcn_cvt_pk_f32_fp8(w10, false); s23 += __builtin_amdgcn_cvt_pk_f32_fp8(w10, true);
          s01 += __builtin_amdgcn_cvt_pk_f32_fp8(w11, false); s23 += __builtin_amdgcn_cvt_pk_f32_fp8(w11, true);
          s01 += __builtin_amdgcn_cvt_pk_f32_fp8(w12, false); s23 += __builtin_amdgcn_cvt_pk_f32_fp8(w12, true);
          s01 += __builtin_amdgcn_cvt_pk_f32_fp8(w13, false); s23 += __builtin_amdgcn_cvt_pk_f32_fp8(w13, true);
          s01 += __builtin_amdgcn_cvt_pk_f32_fp8(w14, false); s23 += __builtin_amdgcn_cvt_pk_f32_fp8(w14, true);
          s01 += __builtin_amdgcn_cvt_pk_f32_fp8(w15, false); s23 += __builtin_amdgcn_cvt_pk_f32_fp8(w15, true);
        } else {
          int j = 0;
          for(; j + 4 <= rem; j += 4){
            int r0 = __builtin_amdgcn_ds_bpermute(bq + ((j+0) << 2), idxv);
            int r1 = __builtin_amdgcn_ds_bpermute(bq + ((j+1) << 2), idxv);
            int r2 = __builtin_amdgcn_ds_bpermute(bq + ((j+2) << 2), idxv);
            int r3 = __builtin_amdgcn_ds_bpermute(bq + ((j+3) << 2), idxv);
            unsigned v0 = g1[((unsigned)r0 << 4) + f];
            unsigned v1 = g1[((unsigned)r1 << 4) + f];
            unsigned v2 = g1[((unsigned)r2 << 4) + f];
            unsigned v3 = g1[((unsigned)r3 << 4) + f];
            s01 += __builtin_amdgcn_cvt_pk_f32_fp8(v0, false);
            s23 += __builtin_amdgcn_cvt_pk_f32_fp8(v0, true);
            s01 += __builtin_amdgcn_cvt_pk_f32_fp8(v1, false);
            s23 += __builtin_amdgcn_cvt_pk_f32_fp8(v1, true);
            s01 += __builtin_amdgcn_cvt_pk_f32_fp8(v2, false);
            s23 += __builtin_amdgcn_cvt_pk_f32_fp8(v2, true);
            s01 += __builtin_amdgcn_cvt_pk_f32_fp8(v3, false);
            s23 += __builtin_amdgcn_cvt_pk_f32_fp8(v3, true);
          }
          for(; j < rem; j++){
            int r0 = __builtin_amdgcn_ds_bpermute(bq + (j << 2), idxv);
            unsigned v0 = g1[((unsigned)r0 << 4) + f];
            s01 += __builtin_amdgcn_cvt_pk_f32_fp8(v0, false);
            s23 += __builtin_amdgcn_cvt_pk_f32_fp8(v0, true);
          }
        }
      }
      float dv = dinv[node];
      float h0 = fmaxf(fmaf(dv, s01.x, bb1.x), 0.f);
      float h1 = fmaxf(fmaf(dv, s01.y, bb1.y), 0.f);
      float h2 = fmaxf(fmaf(dv, s23.x, bb1.z), 0.f);
      float h3 = fmaxf(fmaf(dv, s23.y, bb1.w), 0.f);
      unsigned p0, p1;
      asm("v_cvt_pk_bf16_f32 %0, %1, %2" : "=v"(p0) : "v"(dv*h0), "v"(dv*h1));
      asm("v_cvt_pk_bf16_f32 %0, %1, %2" : "=v"(p1) : "v"(dv*h2), "v"(dv*h3));
      *(uint2*)&us[lrow*72 + f*4] = make_uint2(p0, p1);
    } else {
      *(uint2*)&us[lrow*72 + f*4] = make_uint2(0u, 0u);
    }
  }
  __syncthreads();
  // ---- MFMA phase (classes padded to 48) ----
  int w = t >> 6;
  int ml = lane & 15, q = lane >> 4;
  f32x4 acc0 = {0.f,0.f,0.f,0.f}, acc1 = {0.f,0.f,0.f,0.f}, acc2 = {0.f,0.f,0.f,0.f};
  const unsigned short* brow = &us[(w*16 + ml)*72 + q*8];
  const unsigned short* a0r = &ws2[ml*72 + q*8];
  #pragma unroll
  for(int s = 0; s < 2; s++){
    bf16x8 bb = *(const bf16x8*)(brow + s*32);
    bf16x8 a0 = *(const bf16x8*)(a0r +    0 + s*32);
    bf16x8 a1 = *(const bf16x8*)(a0r + 1152 + s*32);   // +16*72
    bf16x8 a2 = *(const bf16x8*)(a0r + 2304 + s*32);   // +32*72
    acc0 = __builtin_amdgcn_mfma_f32_16x16x32_bf16(a0, bb, acc0, 0, 0, 0);
    acc1 = __builtin_amdgcn_mfma_f32_16x16x32_bf16(a1, bb, acc1, 0, 0, 0);
    acc2 = __builtin_amdgcn_mfma_f32_16x16x32_bf16(a2, bb, acc2, 0, 0, 0);
  }
  // D: col = node (ml), row = class = ctile*16 + q*4 + r -> row dword = ctile*4 + q
  int node = nodeBase + w*16 + ml;
  if(node < n){
    unsigned* gd = (unsigned*)g2;
    unsigned rb = (unsigned)node*10u + q;
    int p;
    p = __builtin_amdgcn_cvt_pk_fp8_f32(acc0[0], acc0[1], 0, false);
    p = __builtin_amdgcn_cvt_pk_fp8_f32(acc0[2], acc0[3], p, true);
    gd[rb + 0] = (unsigned)p;
    p = __builtin_amdgcn_cvt_pk_fp8_f32(acc1[0], acc1[1], 0, false);
    p = __builtin_amdgcn_cvt_pk_fp8_f32(acc1[2], acc1[3], p, true);
    gd[rb + 4] = (unsigned)p;
    if(q < 2){
      p = __builtin_amdgcn_cvt_pk_fp8_f32(acc2[0], acc2[1], 0, false);
      p = __builtin_amdgcn_cvt_pk_fp8_f32(acc2[2], acc2[3], p, true);
      gd[rb + 8] = (unsigned)p;
    }
  }
}

// ---------------- agg2 (static quarters, 16-deep gather pipeline) + log_softmax ----------------
__global__ __launch_bounds__(256) void k_agg2(const unsigned char* __restrict__ g2,
     const int* __restrict__ row_ofs, const int* __restrict__ csr,
     const float* __restrict__ dinv, const float* __restrict__ b2,
     float* __restrict__ out, int N){
  int t = threadIdx.x;
  int lane = t & 63;
  int f = lane & 15;
  int fc = (f < 10) ? f : 0;              // f>=10 lanes duplicate dword0, discarded
  int bq = (lane & 48) << 2;
  int node = blockIdx.x*16 + (t >> 4);
  if(node >= N) return;
  int beg = row_ofs[node], end = row_ofs[node+1];
  const unsigned* gd = (const unsigned*)g2;   // row = 10 dwords (40 fp8)
  unsigned v = gd[(unsigned)node*10u + fc];   // self row
  f32x2 s01 = __builtin_amdgcn_cvt_pk_f32_fp8(v, false);
  f32x2 s23 = __builtin_amdgcn_cvt_pk_f32_fp8(v, true);
  for(int e = beg; e < end; e += 16){
    int rem = end - e; if(rem > 16) rem = 16;
    int idxv = (f < rem) ? csr[e + f] : 0;
    if(rem == 16){
      int r0,r1,r2,r3,r4,r5,r6,r7,r8,r9,r10,r11,r12,r13,r14,r15;
      r0  = __builtin_amdgcn_ds_bpermute(bq +  0, idxv);
      r1  = __builtin_amdgcn_ds_bpermute(bq +  4, idxv);
      r2  = __builtin_amdgcn_ds_bpermute(bq +  8, idxv);
      r3  = __builtin_amdgcn_ds_bpermute(bq + 12, idxv);
      r4  = __builtin_amdgcn_ds_bpermute(bq + 16, idxv);
      r5  = __builtin_amdgcn_ds_bpermute(bq + 20, idxv);
      r6  = __builtin_amdgcn_ds_bpermute(bq + 24, idxv);
      r7  = __builtin_amdgcn_ds_bpermute(bq + 28, idxv);
      r8  = __builtin_amdgcn_ds_bpermute(bq + 32, idxv);
      r9  = __builtin_amdgcn_ds_bpermute(bq + 36, idxv);
      r10 = __builtin_amdgcn_ds_bpermute(bq + 40, idxv);
      r11 = __builtin_amdgcn_ds_bpermute(bq + 44, idxv);
      r12 = __builtin_amdgcn_ds_bpermute(bq + 48, idxv);
      r13 = __builtin_amdgcn_ds_bpermute(bq + 52, idxv);
      r14 = __builtin_amdgcn_ds_bpermute(bq + 56, idxv);
      r15 = __builtin_amdgcn_ds_bpermute(bq + 60, idxv);
      unsigned w0  = gd[(unsigned)r0 *10u + fc];
      unsigned w1  = gd[(unsigned)r1 *10u + fc];
      unsigned w2  = gd[(unsigned)r2 *10u + fc];
      unsigned w3  = gd[(unsigned)r3 *10u + fc];
      unsigned w4  = gd[(unsigned)r4 *10u + fc];
      unsigned w5  = gd[(unsigned)r5 *10u + fc];
      unsigned w6  = gd[(unsigned)r6 *10u + fc];
      unsigned w7  = gd[(unsigned)r7 *10u + fc];
      unsigned w8  = gd[(unsigned)r8 *10u + fc];
      unsigned w9  = gd[(unsigned)r9 *10u + fc];
      unsigned w10 = gd[(unsigned)r10*10u + fc];
      unsigned w11 = gd[(unsigned)r11*10u + fc];
      unsigned w12 = gd[(unsigned)r12*10u + fc];
      unsigned w13 = gd[(unsigned)r13*10u + fc];
      unsigned w14 = gd[(unsigned)r14*10u + fc];
      unsigned w15 = gd[(unsigned)r15*10u + fc];
      s01 += __builtin_amdgcn_cvt_pk_f32_fp8(w0 , false); s23 += __builtin_amdgcn_cvt_pk_f32_fp8(w0 , true);
      s01 += __builtin_amdgcn_cvt_pk_f32_fp8(w1 , false); s23 += __builtin_amdgcn_cvt_pk_f32_fp8(w1 , true);
      s01 += __builtin_amdgcn_cvt_pk_f32_fp8(w2 , false); s23 += __builtin_amdgcn_cvt_pk_f32_fp8(w2 , true);
      s01 += __builtin_amdgcn_cvt_pk_f32_fp8(w3 , false); s23 += __builtin_amdgcn_cvt_pk_f32_fp8(w3 , true);
      s01 += __builtin_amdgcn_cvt_pk_f32_fp8(w4 , false); s23 += __builtin_amdgcn_cvt_pk_f32_fp8(w4 , true);
      s01 += __builtin_amdgcn_cvt_pk_f32_fp8(w5 , false); s23 += __builtin_amdgcn_cvt_pk_f32_fp8(w5 , true);
      s01 += __builtin_amdgcn_cvt_pk_f32_fp8(w6 , false); s23 += __builtin_amdgcn_cvt_pk_f32_fp8(w6 , true);
      s01 += __builtin_amdgcn_cvt_pk_f32_fp8(w7 , false); s23 += __builtin_amdgcn_cvt_pk_f32_fp8(w7 , true);
      s01 += __builtin_amdgcn_cvt_pk_f32_fp8(w8 , false); s23 += __builtin_amdgcn_cvt_pk_f32_fp8(w8 , true);
      s01 += __builtin_amdgcn_cvt_pk_f32_fp8(w9 , false); s23 += __builtin_amdgcn_cvt_pk_f32_fp8(w9 , true);
      s01 += __builtin_amdgcn_cvt_pk_f32_fp8(w10, false); s23 += __builtin_amdgcn_cvt_pk_f32_fp8(w10, true);
      s01 += __builtin_amdgcn_cvt_pk_f32_fp8(w11, false); s23 += __builtin_amdgcn_cvt_pk_f32_fp8(w11, true);
      s01 += __builtin_amdgcn_cvt_pk_f32_fp8(w12, false); s23 += __builtin_amdgcn_cvt_pk_f32_fp8(w12, true);
      s01 += __builtin_amdgcn_cvt_pk_f32_fp8(w13, false); s23 += __builtin_amdgcn_cvt_pk_f32_fp8(w13, true);
      s01 += __builtin_amdgcn_cvt_pk_f32_fp8(w14, false); s23 += __builtin_amdgcn_cvt_pk_f32_fp8(w14, true);
      s01 += __builtin_amdgcn_cvt_pk_f32_fp8(w15, false); s23 += __builtin_amdgcn_cvt_pk_f32_fp8(w15, true);
    } else {
      int j = 0;
      for(; j + 4 <= rem; j += 4){
        int r0 = __builtin_amdgcn_ds_bpermute(bq + ((j+0) << 2), idxv);
        int r1 = __builtin_amdgcn_ds_bpermute(bq + ((j+1) << 2), idxv);
        int r2 = __builtin_amdgcn_ds_bpermute(bq + ((j+2) << 2), idxv);
        int r3 = __builtin_amdgcn_ds_bpermute(bq + ((j+3) << 2), idxv);
        unsigned v0 = gd[(unsigned)r0*10u + fc];
        unsigned v1 = gd[(unsigned)r1*10u + fc];
        unsigned v2 = gd[(unsigned)r2*10u + fc];
        unsigned v3 = gd[(unsigned)r3*10u + fc];
        s01 += __builtin_amdgcn_cvt_pk_f32_fp8(v0, false);
        s23 += __builtin_amdgcn_cvt_pk_f32_fp8(v0, true);
        s01 += __builtin_amdgcn_cvt_pk_f32_fp8(v1, false);
        s23 += __builtin_amdgcn_cvt_pk_f32_fp8(v1, true);
        s01 += __builtin_amdgcn_cvt_pk_f32_fp8(v2, false);
        s23 += __builtin_amdgcn_cvt_pk_f32_fp8(v2, true);
        s01 += __builtin_amdgcn_cvt_pk_f32_fp8(v3, false);
        s23 += __builtin_amdgcn_cvt_pk_f32_fp8(v3, true);
      }
      for(; j < rem; j++){
        int r0 = __builtin_amdgcn_ds_bpermute(bq + (j << 2), idxv);
        unsigned v0 = gd[(unsigned)r0*10u + fc];
        s01 += __builtin_amdgcn_cvt_pk_f32_fp8(v0, false);
        s23 += __builtin_amdgcn_cvt_pk_f32_fp8(v0, true);
      }
    }
  }
  float dv = dinv[node];
  float4 bb = ((const float4*)b2)[fc];
  float l0 = fmaf(dv, s01.x, bb.x);
  float l1 = fmaf(dv, s01.y, bb.y);
  float l2 = fmaf(dv, s23.x, bb.z);
  float l3 = fmaf(dv, s23.y, bb.w);
  bool valid = (f < 10);
  float m = valid ? fmaxf(fmaxf(l0,l1), fmaxf(l2,l3)) : -INFINITY;
  m = fmaxf(m, __shfl_xor(m,1,64)); m = fmaxf(m, __shfl_xor(m,2,64));
  m = fmaxf(m, __shfl_xor(m,4,64)); m = fmaxf(m, __shfl_xor(m,8,64));
  float ex = valid ? (expf(l0-m)+expf(l1-m)) + (expf(l2-m)+expf(l3-m)) : 0.f;
  ex += __shfl_xor(ex,1,64); ex += __shfl_xor(ex,2,64);
  ex += __shfl_xor(ex,4,64); ex += __shfl_xor(ex,8,64);
  float ll = logf(ex);
  if(valid){
    ((float4*)out)[(unsigned)node*10u + f] = make_float4(l0-m-ll, l1-m-ll, l2-m-ll, l3-m-ll);
  }
}

// ---------------- launch ----------------

extern "C" void kernel_launch(void* const* d_in, const int* in_sizes, int n_in,
                              void* d_out, int out_size, void* d_ws, size_t ws_size,
                              hipStream_t stream){
  const float* x  = (const float*)d_in[0];
  const int*   ei = (const int*)  d_in[1];
  const float* W1 = (const float*)d_in[2];
  const float* b1 = (const float*)d_in[3];
  const float* W2 = (const float*)d_in[4];
  const float* b2 = (const float*)d_in[5];
  float* out = (float*)d_out;

  int N = in_sizes[0] / 128;        // 100000
  int E = in_sizes[1] / 2;          // 1600000
  const int* src = ei;
  const int* dst = ei + E;
  int NB = (N + NPB - 1) >> BSH;    // 391

  char* w = (char*)d_ws;
  auto alloc = [&](size_t bytes) -> char* {
    char* p = w;
    w += (bytes + 511) & ~(size_t)511;
    return p;
  };
  int*   bcnt    = (int*)  alloc((size_t)NB*4);
  int*   bofs    = (int*)  alloc((size_t)(NB+1)*4);
  int*   bcur    = (int*)  alloc((size_t)NB*4);
  int*   row_ofs = (int*)  alloc((size_t)(N+1)*4);
  float* dinv    = (float*)alloc((size_t)N*4);
  unsigned int* binned = (unsigned int*)alloc((size_t)E*4);
  int*   csr     = (int*)  alloc((size_t)E*4);
  unsigned int*   g1 = (unsigned int*)  alloc((size_t)N*64);   // fp8, 64 B rows
  unsigned char*  g2 = (unsigned char*) alloc((size_t)N*40);   // fp8, 40 B rows
  unsigned short* w1t = (unsigned short*)alloc((size_t)64*128*2); // W1^T bf16
  unsigned short* w2t = (unsigned short*)alloc((size_t)48*64*2);  // W2^T bf16 (padded)

  int NBH = (E + HIST_CHUNK - 1)/HIST_CHUNK;   // 391 hist blocks

  hipMemsetAsync(bcnt, 0, (size_t)NB*4, stream);
  k_bhist   <<<NBH+2, 256, 0, stream>>>(dst, E, bcnt, NB, NBH, W1, W2, w1t, w2t);
  k_bscan   <<<1, 1024, 0, stream>>>(bcnt, bofs, bcur, NB, E);
  k_binpass <<<(E+BIN_CHUNK-1)/BIN_CHUNK, 256, 0, stream>>>(src, dst, E, bcur, binned, NB);
  k_bscatter<<<NB, 256, 0, stream>>>(binned, bofs, csr, row_ofs, dinv, N, E, NB);

  k_gemm1   <<<(N+127)/128, 256, 0, stream>>>(x, w1t, dinv, g1, N);
  k_agg1g2  <<<(N+63)/64, 256, 0, stream>>>(g1, row_ofs, csr, dinv, b1, w2t, g2, N);
  k_agg2    <<<(N+15)/16, 256, 0, stream>>>(g2, row_ofs, csr, dinv, b2, out, N);
}

// Round 8
// 212.602 us; speedup vs baseline: 1.0791x; 1.0306x over previous
//
#include <hip/hip_runtime.h>
#include <math.h>

#define NPB 256           // nodes per bucket
#define BSH 8
#define MAXNB 400
#define BIN_CHUNK 4096
#define HIST_CHUNK 4096

typedef __attribute__((ext_vector_type(8))) short bf16x8;
typedef __attribute__((ext_vector_type(4))) float f32x4;
typedef __attribute__((ext_vector_type(2))) float f32x2;

__device__ __forceinline__ unsigned short f2bf(float f){
  unsigned int u = __float_as_uint(f);
  unsigned int r = (u + 0x7FFFu + ((u >> 16) & 1u)) >> 16;   // RNE
  return (unsigned short)r;
}

// pack 8 f32 -> bf16x8 via v_cvt_pk_bf16_f32 (RNE, 1 inst / 2 floats)
__device__ __forceinline__ bf16x8 cvt8(float4 a, float4 b){
  union { unsigned u[4]; bf16x8 v; } r;
  asm("v_cvt_pk_bf16_f32 %0, %1, %2" : "=v"(r.u[0]) : "v"(a.x), "v"(a.y));
  asm("v_cvt_pk_bf16_f32 %0, %1, %2" : "=v"(r.u[1]) : "v"(a.z), "v"(a.w));
  asm("v_cvt_pk_bf16_f32 %0, %1, %2" : "=v"(r.u[2]) : "v"(b.x), "v"(b.y));
  asm("v_cvt_pk_bf16_f32 %0, %1, %2" : "=v"(r.u[3]) : "v"(b.z), "v"(b.w));
  return r.v;
}

// ---------------- CSR build (bucketed two-pass) + weight prep + zero-row init ----------------

__global__ __launch_bounds__(256) void k_bhist(const int* __restrict__ dst, int E,
                                               int* __restrict__ bcnt, int NB, int NBH,
                                               const float* __restrict__ W1,
                                               const float* __restrict__ W2,
                                               unsigned short* __restrict__ w1t,
                                               unsigned short* __restrict__ w2t,
                                               unsigned* __restrict__ g1,
                                               unsigned* __restrict__ g2d, int N){
  __shared__ int l[MAXNB];
  int t = threadIdx.x, b = blockIdx.x;
  if(b >= NBH){
    if(b == NBH){
      for(int i = t; i < 8192; i += 256){
        int k = i >> 6, f = i & 63;
        w1t[f*128 + k] = f2bf(W1[i]);
      }
      if(t < 16) g1[((size_t)(unsigned)N << 4) + t] = 0;   // zero row for agg1
    } else {
      for(int i = t; i < 3072; i += 256){
        int c = i >> 6, k = i & 63;
        w2t[c*64 + k] = (c < 40) ? f2bf(W2[k*40 + c]) : (unsigned short)0;
      }
      if(t < 16) g2d[((size_t)(unsigned)N << 4) + t] = 0;  // zero row for agg2
    }
    return;
  }
  int base = b*HIST_CHUNK;
  int end = base + HIST_CHUNK; if(end > E) end = E;
  for(int i = t; i < NB; i += 256) l[i] = 0;
  __syncthreads();
  for(int i = base + t; i < end; i += 256) atomicAdd(&l[dst[i] >> BSH], 1);
  __syncthreads();
  for(int i = t; i < NB; i += 256){ int c = l[i]; if(c) atomicAdd(&bcnt[i], c); }
}

__global__ void k_bscan(const int* __restrict__ bcnt, int* __restrict__ bofs,
                        int* __restrict__ bcur, int NB, int E){
  __shared__ int sh[1024];
  int t = threadIdx.x;
  int c0 = (2*t   < NB) ? bcnt[2*t]   : 0;
  int c1 = (2*t+1 < NB) ? bcnt[2*t+1] : 0;
  sh[t] = c0 + c1; __syncthreads();
  for(int off = 1; off < 1024; off <<= 1){
    int v = (t >= off) ? sh[t - off] : 0;
    __syncthreads();
    sh[t] += v;
    __syncthreads();
  }
  int pairEx = sh[t] - (c0 + c1);
  if(2*t   < NB){ bofs[2*t]   = pairEx;      bcur[2*t]   = pairEx; }
  if(2*t+1 < NB){ bofs[2*t+1] = pairEx + c0; bcur[2*t+1] = pairEx + c0; }
  if(t == 0) bofs[NB] = E;
}

__global__ __launch_bounds__(256) void k_binpass(const int* __restrict__ src,
                          const int* __restrict__ dst, int E,
                          int* __restrict__ bcur, unsigned int* __restrict__ binned, int NB){
  __shared__ int lcnt[MAXNB];
  __shared__ int lpos[MAXNB];
  int t = threadIdx.x;
  int base = blockIdx.x * BIN_CHUNK;
  int end = base + BIN_CHUNK; if(end > E) end = E;
  for(int b = t; b < NB; b += 256) lcnt[b] = 0;
  __syncthreads();
  for(int i = base + t; i < end; i += 256)
    atomicAdd(&lcnt[dst[i] >> BSH], 1);
  __syncthreads();
  for(int b = t; b < NB; b += 256){
    int c = lcnt[b];
    lpos[b] = c ? atomicAdd(&bcur[b], c) : 0;
  }
  __syncthreads();
  for(int i = base + t; i < end; i += 256){
    int d = dst[i];
    int b = d >> BSH;
    unsigned int rec = (unsigned int)src[i] | ((unsigned int)(d & (NPB-1)) << 17);
    int p = atomicAdd(&lpos[b], 1);
    binned[p] = rec;
  }
}

// one block per 256-node bucket: LDS hist + 4-wave scan -> row_ofs, dinv, csr
__global__ __launch_bounds__(256) void k_bscatter(const unsigned int* __restrict__ binned,
     const int* __restrict__ bofs, int* __restrict__ csr, int* __restrict__ row_ofs,
     float* __restrict__ dinv, int N, int E, int NB){
  __shared__ int lcnt[NPB];
  __shared__ int lofs[NPB];
  __shared__ int lcur[NPB];
  __shared__ int wsum[4];
  int b = blockIdx.x, t = threadIdx.x;
  int beg = bofs[b], end = bofs[b+1];
  lcnt[t] = 0;
  __syncthreads();
  for(int i = beg + t; i < end; i += 256) atomicAdd(&lcnt[binned[i] >> 17], 1);
  __syncthreads();
  int c = lcnt[t];
  int lane = t & 63, wid = t >> 6;
  int v = c;
  #pragma unroll
  for(int off = 1; off < 64; off <<= 1){
    int nv = __shfl_up(v, off, 64);
    if(lane >= off) v += nv;
  }
  if(lane == 63) wsum[wid] = v;
  __syncthreads();
  int wpre = 0;
  #pragma unroll
  for(int k2 = 0; k2 < 4; k2++) if(k2 < wid) wpre += wsum[k2];
  int ex = wpre + v - c;
  lofs[t] = beg + ex; lcur[t] = 0;
  int node = (b << BSH) + t;
  if(node < N){
    row_ofs[node] = beg + ex;
    dinv[node] = rsqrtf((float)(c + 1));   // +1 self loop
  }
  __syncthreads();
  for(int i = beg + t; i < end; i += 256){
    unsigned int rec = binned[i];
    int dl = rec >> 17;
    int pos = lofs[dl] + atomicAdd(&lcur[dl], 1);
    csr[pos] = (int)(rec & 0x1FFFFu);
  }
  if(b == NB-1 && t == 0) row_ofs[N] = E;
}

// ---------------- GEMM1 (MFMA bf16): g1 = fp8( dinv * (x @ W1) ) ----------------
__global__ __launch_bounds__(256) void k_gemm1(const float* __restrict__ x,
                        const unsigned short* __restrict__ w1t,
                        const float* __restrict__ dinv, unsigned int* __restrict__ g1, int n){
  __shared__ unsigned short xs[128*136];  // x tile bf16 [node][k]
  __shared__ unsigned short wt[64*136];   // W1^T bf16 [feat][k]
  int tid = threadIdx.x;
  int nodeBase = blockIdx.x*128;
  for(int i = tid; i < 1024; i += 256){
    int f = i >> 4, seg = i & 15;
    *(uint4*)&wt[f*136 + seg*8] = *(const uint4*)&w1t[f*128 + seg*8];
  }
  {
    const float4* x4 = (const float4*)x;
    for(int i = tid; i < 2048; i += 256){
      int node = i >> 4, seg = i & 15;     // 8 floats per chunk
      float4 va = make_float4(0.f,0.f,0.f,0.f), vb = va;
      if(nodeBase + node < n){
        va = x4[(size_t)(nodeBase + node)*32 + seg*2];
        vb = x4[(size_t)(nodeBase + node)*32 + seg*2 + 1];
      }
      *(bf16x8*)&xs[node*136 + seg*8] = cvt8(va, vb);
    }
  }
  __syncthreads();

  int w = tid >> 6, lane = tid & 63;
  int ml = lane & 15, q = lane >> 4;
  int n0 = nodeBase + w*32 + ml;
  int n1 = n0 + 16;
  bool vn0 = n0 < n, vn1 = n1 < n;

  f32x4 a00 = {0.f,0.f,0.f,0.f}, a01 = {0.f,0.f,0.f,0.f},
        a02 = {0.f,0.f,0.f,0.f}, a03 = {0.f,0.f,0.f,0.f};
  f32x4 a10 = {0.f,0.f,0.f,0.f}, a11 = {0.f,0.f,0.f,0.f},
        a12 = {0.f,0.f,0.f,0.f}, a13 = {0.f,0.f,0.f,0.f};
  const unsigned short* brow = &xs[(w*32 + ml)*136 + q*8];
  const unsigned short* arow = &wt[ml*136 + q*8];
  #pragma unroll
  for(int s = 0; s < 4; s++){
    bf16x8 bb0 = *(const bf16x8*)(brow +        s*32);
    bf16x8 bb1 = *(const bf16x8*)(brow + 2176 + s*32);   // +16*136
    bf16x8 a0 = *(const bf16x8*)(arow +    0 + s*32);
    bf16x8 a1 = *(const bf16x8*)(arow + 2176 + s*32);
    bf16x8 a2 = *(const bf16x8*)(arow + 4352 + s*32);
    bf16x8 a3 = *(const bf16x8*)(arow + 6528 + s*32);
    a00 = __builtin_amdgcn_mfma_f32_16x16x32_bf16(a0, bb0, a00, 0, 0, 0);
    a01 = __builtin_amdgcn_mfma_f32_16x16x32_bf16(a1, bb0, a01, 0, 0, 0);
    a02 = __builtin_amdgcn_mfma_f32_16x16x32_bf16(a2, bb0, a02, 0, 0, 0);
    a03 = __builtin_amdgcn_mfma_f32_16x16x32_bf16(a3, bb0, a03, 0, 0, 0);
    a10 = __builtin_amdgcn_mfma_f32_16x16x32_bf16(a0, bb1, a10, 0, 0, 0);
    a11 = __builtin_amdgcn_mfma_f32_16x16x32_bf16(a1, bb1, a11, 0, 0, 0);
    a12 = __builtin_amdgcn_mfma_f32_16x16x32_bf16(a2, bb1, a12, 0, 0, 0);
    a13 = __builtin_amdgcn_mfma_f32_16x16x32_bf16(a3, bb1, a13, 0, 0, 0);
  }
  if(vn0){
    float dv = dinv[n0];
    unsigned base16 = ((unsigned)n0 << 4) + q;
    int p;
    p = __builtin_amdgcn_cvt_pk_fp8_f32(a00[0]*dv, a00[1]*dv, 0, false);
    p = __builtin_amdgcn_cvt_pk_fp8_f32(a00[2]*dv, a00[3]*dv, p, true);
    g1[base16 +  0] = (unsigned)p;
    p = __builtin_amdgcn_cvt_pk_fp8_f32(a01[0]*dv, a01[1]*dv, 0, false);
    p = __builtin_amdgcn_cvt_pk_fp8_f32(a01[2]*dv, a01[3]*dv, p, true);
    g1[base16 +  4] = (unsigned)p;
    p = __builtin_amdgcn_cvt_pk_fp8_f32(a02[0]*dv, a02[1]*dv, 0, false);
    p = __builtin_amdgcn_cvt_pk_fp8_f32(a02[2]*dv, a02[3]*dv, p, true);
    g1[base16 +  8] = (unsigned)p;
    p = __builtin_amdgcn_cvt_pk_fp8_f32(a03[0]*dv, a03[1]*dv, 0, false);
    p = __builtin_amdgcn_cvt_pk_fp8_f32(a03[2]*dv, a03[3]*dv, p, true);
    g1[base16 + 12] = (unsigned)p;
  }
  if(vn1){
    float dv = dinv[n1];
    unsigned base16 = ((unsigned)n1 << 4) + q;
    int p;
    p = __builtin_amdgcn_cvt_pk_fp8_f32(a10[0]*dv, a10[1]*dv, 0, false);
    p = __builtin_amdgcn_cvt_pk_fp8_f32(a10[2]*dv, a10[3]*dv, p, true);
    g1[base16 +  0] = (unsigned)p;
    p = __builtin_amdgcn_cvt_pk_fp8_f32(a11[0]*dv, a11[1]*dv, 0, false);
    p = __builtin_amdgcn_cvt_pk_fp8_f32(a11[2]*dv, a11[3]*dv, p, true);
    g1[base16 +  4] = (unsigned)p;
    p = __builtin_amdgcn_cvt_pk_fp8_f32(a12[0]*dv, a12[1]*dv, 0, false);
    p = __builtin_amdgcn_cvt_pk_fp8_f32(a12[2]*dv, a12[3]*dv, p, true);
    g1[base16 +  8] = (unsigned)p;
    p = __builtin_amdgcn_cvt_pk_fp8_f32(a13[0]*dv, a13[1]*dv, 0, false);
    p = __builtin_amdgcn_cvt_pk_fp8_f32(a13[2]*dv, a13[3]*dv, p, true);
    g1[base16 + 12] = (unsigned)p;
  }
}

#define ACC8(W) { \
  s0 += __builtin_amdgcn_cvt_pk_f32_fp8(W.x, false); \
  s1 += __builtin_amdgcn_cvt_pk_f32_fp8(W.x, true);  \
  s2 += __builtin_amdgcn_cvt_pk_f32_fp8(W.y, false); \
  s3 += __builtin_amdgcn_cvt_pk_f32_fp8(W.y, true); }

// ---------------- fused agg1 + gemm2 (paired nodes, zero-row-masked, uniform loop) ----------------
// 64 nodes/block. Each 16-lane quarter processes 2 nodes at a time (low 8 lanes =
// node A, high 8 = node B); lane hl owns feats 8hl..8hl+7 via one uint2 load/edge.
// Out-of-range edge slots stage the zero row (index NZ) -> no tails, no masks.
__global__ __launch_bounds__(256) void k_agg1g2(const unsigned* __restrict__ g1,
    const int* __restrict__ row_ofs, const int* __restrict__ csr,
    const float* __restrict__ dinv, const float* __restrict__ b1,
    const unsigned short* __restrict__ w2t, unsigned* __restrict__ g2d, int n){
  __shared__ unsigned short us[64*72];    // u tile bf16 [node][k]
  __shared__ unsigned short ws2[48*72];   // W2^T bf16 [class][k]
  int t = threadIdx.x;
  int nodeBase = blockIdx.x*64;
  for(int i = t; i < 384; i += 256){
    int row = i >> 3, seg = i & 7;
    *(uint4*)&ws2[row*72 + seg*8] = *(const uint4*)&w2t[row*64 + seg*8];
  }
  int lane = t & 63;
  int hl = lane & 7;                      // position within half
  int half = (lane >> 3) & 1;             // 0 = node A, 1 = node B
  int bqh = ((lane & 48) << 2) + half*32; // bpermute byte base of own half
  int qg = t >> 4;                        // quarter index 0..15
  const char* g1c = (const char*)g1;
  float4 b1a = ((const float4*)b1)[hl*2];
  float4 b1b = ((const float4*)b1)[hl*2+1];
  #pragma unroll 1
  for(int p = 0; p < 2; p++){
    int lrow = qg*4 + p*2 + half;
    int node = nodeBase + lrow;
    f32x2 s0={0.f,0.f}, s1={0.f,0.f}, s2={0.f,0.f}, s3={0.f,0.f};
    int e = 0, end = 0; float dv = 0.f;
    if(node < n){
      e = row_ofs[node]; end = row_ofs[node+1];
      dv = dinv[node];
      uint2 sv = *(const uint2*)(g1c + ((size_t)(unsigned)node << 6) + (hl<<3));
      s0 = __builtin_amdgcn_cvt_pk_f32_fp8(sv.x, false);
      s1 = __builtin_amdgcn_cvt_pk_f32_fp8(sv.x, true);
      s2 = __builtin_amdgcn_cvt_pk_f32_fp8(sv.y, false);
      s3 = __builtin_amdgcn_cvt_pk_f32_fp8(sv.y, true);
    }
    for(; e < end; e += 8){
      int idxv = (e + hl < end) ? csr[e + hl] : n;   // n = zero row
      int r0 = __builtin_amdgcn_ds_bpermute(bqh +  0, idxv);
      int r1 = __builtin_amdgcn_ds_bpermute(bqh +  4, idxv);
      int r2 = __builtin_amdgcn_ds_bpermute(bqh +  8, idxv);
      int r3 = __builtin_amdgcn_ds_bpermute(bqh + 12, idxv);
      int r4 = __builtin_amdgcn_ds_bpermute(bqh + 16, idxv);
      int r5 = __builtin_amdgcn_ds_bpermute(bqh + 20, idxv);
      int r6 = __builtin_amdgcn_ds_bpermute(bqh + 24, idxv);
      int r7 = __builtin_amdgcn_ds_bpermute(bqh + 28, idxv);
      uint2 w0 = *(const uint2*)(g1c + ((size_t)(unsigned)r0 << 6) + (hl<<3));
      uint2 w1 = *(const uint2*)(g1c + ((size_t)(unsigned)r1 << 6) + (hl<<3));
      uint2 w2 = *(const uint2*)(g1c + ((size_t)(unsigned)r2 << 6) + (hl<<3));
      uint2 w3 = *(const uint2*)(g1c + ((size_t)(unsigned)r3 << 6) + (hl<<3));
      uint2 w4 = *(const uint2*)(g1c + ((size_t)(unsigned)r4 << 6) + (hl<<3));
      uint2 w5 = *(const uint2*)(g1c + ((size_t)(unsigned)r5 << 6) + (hl<<3));
      uint2 w6 = *(const uint2*)(g1c + ((size_t)(unsigned)r6 << 6) + (hl<<3));
      uint2 w7 = *(const uint2*)(g1c + ((size_t)(unsigned)r7 << 6) + (hl<<3));
      ACC8(w0); ACC8(w1); ACC8(w2); ACC8(w3);
      ACC8(w4); ACC8(w5); ACC8(w6); ACC8(w7);
    }
    unsigned p0 = 0, p1 = 0, p2 = 0, p3 = 0;
    if(node < n){
      float h0 = fmaxf(fmaf(dv, s0.x, b1a.x), 0.f);
      float h1 = fmaxf(fmaf(dv, s0.y, b1a.y), 0.f);
      float h2 = fmaxf(fmaf(dv, s1.x, b1a.z), 0.f);
      float h3 = fmaxf(fmaf(dv, s1.y, b1a.w), 0.f);
      float h4 = fmaxf(fmaf(dv, s2.x, b1b.x), 0.f);
      float h5 = fmaxf(fmaf(dv, s2.y, b1b.y), 0.f);
      float h6 = fmaxf(fmaf(dv, s3.x, b1b.z), 0.f);
      float h7 = fmaxf(fmaf(dv, s3.y, b1b.w), 0.f);
      asm("v_cvt_pk_bf16_f32 %0, %1, %2" : "=v"(p0) : "v"(dv*h0), "v"(dv*h1));
      asm("v_cvt_pk_bf16_f32 %0, %1, %2" : "=v"(p1) : "v"(dv*h2), "v"(dv*h3));
      asm("v_cvt_pk_bf16_f32 %0, %1, %2" : "=v"(p2) : "v"(dv*h4), "v"(dv*h5));
      asm("v_cvt_pk_bf16_f32 %0, %1, %2" : "=v"(p3) : "v"(dv*h6), "v"(dv*h7));
    }
    *(uint4*)&us[lrow*72 + hl*8] = make_uint4(p0, p1, p2, p3);
  }
  __syncthreads();
  // ---- MFMA phase (classes padded to 48) ----
  int w = t >> 6;
  int ml = lane & 15, q = lane >> 4;
  f32x4 acc0 = {0.f,0.f,0.f,0.f}, acc1 = {0.f,0.f,0.f,0.f}, acc2 = {0.f,0.f,0.f,0.f};
  const unsigned short* brow = &us[(w*16 + ml)*72 + q*8];
  const unsigned short* a0r = &ws2[ml*72 + q*8];
  #pragma unroll
  for(int s = 0; s < 2; s++){
    bf16x8 bb = *(const bf16x8*)(brow + s*32);
    bf16x8 a0 = *(const bf16x8*)(a0r +    0 + s*32);
    bf16x8 a1 = *(const bf16x8*)(a0r + 1152 + s*32);   // +16*72
    bf16x8 a2 = *(const bf16x8*)(a0r + 2304 + s*32);   // +32*72
    acc0 = __builtin_amdgcn_mfma_f32_16x16x32_bf16(a0, bb, acc0, 0, 0, 0);
    acc1 = __builtin_amdgcn_mfma_f32_16x16x32_bf16(a1, bb, acc1, 0, 0, 0);
    acc2 = __builtin_amdgcn_mfma_f32_16x16x32_bf16(a2, bb, acc2, 0, 0, 0);
  }
  // D: col = node (ml), row = class = ctile*16 + q*4 + r -> row dword = ctile*4 + q
  int node = nodeBase + w*16 + ml;
  if(node < n){
    unsigned rb = ((unsigned)node << 4) + q;   // 64-B padded rows
    int p;
    p = __builtin_amdgcn_cvt_pk_fp8_f32(acc0[0], acc0[1], 0, false);
    p = __builtin_amdgcn_cvt_pk_fp8_f32(acc0[2], acc0[3], p, true);
    g2d[rb + 0] = (unsigned)p;
    p = __builtin_amdgcn_cvt_pk_fp8_f32(acc1[0], acc1[1], 0, false);
    p = __builtin_amdgcn_cvt_pk_fp8_f32(acc1[2], acc1[3], p, true);
    g2d[rb + 4] = (unsigned)p;
    if(q < 2){
      p = __builtin_amdgcn_cvt_pk_fp8_f32(acc2[0], acc2[1], 0, false);
      p = __builtin_amdgcn_cvt_pk_fp8_f32(acc2[2], acc2[3], p, true);
      g2d[rb + 8] = (unsigned)p;
    } else {
      g2d[rb + 8] = 0;                         // dwords 10,11 padding
    }
    g2d[rb + 12] = 0;                          // dwords 12..15 padding
  }
}

// ---------------- agg2 (paired nodes, zero-row-masked) + bias + log_softmax ----------------
// 32 nodes/block; quarter = 2 nodes (A low 8 lanes, B high 8); lane hl owns
// classes 8hl..8hl+7 (valid hl<5); g2 rows padded to 64 B (one line per row).
__global__ __launch_bounds__(256) void k_agg2(const unsigned* __restrict__ g2d,
     const int* __restrict__ row_ofs, const int* __restrict__ csr,
     const float* __restrict__ dinv, const float* __restrict__ b2,
     float* __restrict__ out, int N){
  int t = threadIdx.x;
  int lane = t & 63;
  int hl = lane & 7;
  int half = (lane >> 3) & 1;
  int bqh = ((lane & 48) << 2) + half*32;
  int qg = t >> 4;
  int node = blockIdx.x*32 + qg*2 + half;
  const char* g2c = (const char*)g2d;
  int hc = (hl < 5) ? hl : 0;
  float4 b2a = ((const float4*)b2)[hc*2];
  float4 b2b = ((const float4*)b2)[hc*2+1];
  f32x2 s0={0.f,0.f}, s1={0.f,0.f}, s2={0.f,0.f}, s3={0.f,0.f};
  int e = 0, end = 0; float dv = 0.f;
  if(node < N){
    e = row_ofs[node]; end = row_ofs[node+1];
    dv = dinv[node];
    uint2 sv = *(const uint2*)(g2c + ((size_t)(unsigned)node << 6) + (hl<<3));
    s0 = __builtin_amdgcn_cvt_pk_f32_fp8(sv.x, false);
    s1 = __builtin_amdgcn_cvt_pk_f32_fp8(sv.x, true);
    s2 = __builtin_amdgcn_cvt_pk_f32_fp8(sv.y, false);
    s3 = __builtin_amdgcn_cvt_pk_f32_fp8(sv.y, true);
  }
  for(; e < end; e += 8){
    int idxv = (e + hl < end) ? csr[e + hl] : N;   // N = zero row
    int r0 = __builtin_amdgcn_ds_bpermute(bqh +  0, idxv);
    int r1 = __builtin_amdgcn_ds_bpermute(bqh +  4, idxv);
    int r2 = __builtin_amdgcn_ds_bpermute(bqh +  8, idxv);
    int r3 = __builtin_amdgcn_ds_bpermute(bqh + 12, idxv);
    int r4 = __builtin_amdgcn_ds_bpermute(bqh + 16, idxv);
    int r5 = __builtin_amdgcn_ds_bpermute(bqh + 20, idxv);
    int r6 = __builtin_amdgcn_ds_bpermute(bqh + 24, idxv);
    int r7 = __builtin_amdgcn_ds_bpermute(bqh + 28, idxv);
    uint2 w0 = *(const uint2*)(g2c + ((size_t)(unsigned)r0 << 6) + (hl<<3));
    uint2 w1 = *(const uint2*)(g2c + ((size_t)(unsigned)r1 << 6) + (hl<<3));
    uint2 w2 = *(const uint2*)(g2c + ((size_t)(unsigned)r2 << 6) + (hl<<3));
    uint2 w3 = *(const uint2*)(g2c + ((size_t)(unsigned)r3 << 6) + (hl<<3));
    uint2 w4 = *(const uint2*)(g2c + ((size_t)(unsigned)r4 << 6) + (hl<<3));
    uint2 w5 = *(const uint2*)(g2c + ((size_t)(unsigned)r5 << 6) + (hl<<3));
    uint2 w6 = *(const uint2*)(g2c + ((size_t)(unsigned)r6 << 6) + (hl<<3));
    uint2 w7 = *(const uint2*)(g2c + ((size_t)(unsigned)r7 << 6) + (hl<<3));
    ACC8(w0); ACC8(w1); ACC8(w2); ACC8(w3);
    ACC8(w4); ACC8(w5); ACC8(w6); ACC8(w7);
  }
  float l0 = fmaf(dv, s0.x, b2a.x);
  float l1 = fmaf(dv, s0.y, b2a.y);
  float l2 = fmaf(dv, s1.x, b2a.z);
  float l3 = fmaf(dv, s1.y, b2a.w);
  float l4 = fmaf(dv, s2.x, b2b.x);
  float l5 = fmaf(dv, s2.y, b2b.y);
  float l6 = fmaf(dv, s3.x, b2b.z);
  float l7 = fmaf(dv, s3.y, b2b.w);
  bool valid = (hl < 5);
  float m = valid ? fmaxf(fmaxf(fmaxf(l0,l1), fmaxf(l2,l3)),
                          fmaxf(fmaxf(l4,l5), fmaxf(l6,l7))) : -INFINITY;
  m = fmaxf(m, __shfl_xor(m,1,64)); m = fmaxf(m, __shfl_xor(m,2,64));
  m = fmaxf(m, __shfl_xor(m,4,64));
  float ex = valid ? ((expf(l0-m)+expf(l1-m)) + (expf(l2-m)+expf(l3-m)))
                   + ((expf(l4-m)+expf(l5-m)) + (expf(l6-m)+expf(l7-m))) : 0.f;
  ex += __shfl_xor(ex,1,64); ex += __shfl_xor(ex,2,64);
  ex += __shfl_xor(ex,4,64);
  float ll = logf(ex);
  if(valid && node < N){
    float4* o4 = (float4*)out;
    o4[(unsigned)node*10u + hl*2    ] = make_float4(l0-m-ll, l1-m-ll, l2-m-ll, l3-m-ll);
    o4[(unsigned)node*10u + hl*2 + 1] = make_float4(l4-m-ll, l5-m-ll, l6-m-ll, l7-m-ll);
  }
}

// ---------------- launch ----------------

extern "C" void kernel_launch(void* const* d_in, const int* in_sizes, int n_in,
                              void* d_out, int out_size, void* d_ws, size_t ws_size,
                              hipStream_t stream){
  const float* x  = (const float*)d_in[0];
  const int*   ei = (const int*)  d_in[1];
  const float* W1 = (const float*)d_in[2];
  const float* b1 = (const float*)d_in[3];
  const float* W2 = (const float*)d_in[4];
  const float* b2 = (const float*)d_in[5];
  float* out = (float*)d_out;

  int N = in_sizes[0] / 128;        // 100000
  int E = in_sizes[1] / 2;          // 1600000
  const int* src = ei;
  const int* dst = ei + E;
  int NB = (N + NPB - 1) >> BSH;    // 391

  char* w = (char*)d_ws;
  auto alloc = [&](size_t bytes) -> char* {
    char* p = w;
    w += (bytes + 511) & ~(size_t)511;
    return p;
  };
  int*   bcnt    = (int*)  alloc((size_t)NB*4);
  int*   bofs    = (int*)  alloc((size_t)(NB+1)*4);
  int*   bcur    = (int*)  alloc((size_t)NB*4);
  int*   row_ofs = (int*)  alloc((size_t)(N+1)*4);
  float* dinv    = (float*)alloc((size_t)N*4);
  unsigned int* binned = (unsigned int*)alloc((size_t)E*4);
  int*   csr     = (int*)  alloc((size_t)E*4);
  unsigned int*   g1 = (unsigned int*)  alloc((size_t)(N+1)*64); // fp8, 64-B rows + zero row
  unsigned int*   g2 = (unsigned int*)  alloc((size_t)(N+1)*64); // fp8, 64-B rows + zero row
  unsigned short* w1t = (unsigned short*)alloc((size_t)64*128*2); // W1^T bf16
  unsigned short* w2t = (unsigned short*)alloc((size_t)48*64*2);  // W2^T bf16 (padded)

  int NBH = (E + HIST_CHUNK - 1)/HIST_CHUNK;   // 391 hist blocks

  hipMemsetAsync(bcnt, 0, (size_t)NB*4, stream);
  k_bhist   <<<NBH+2, 256, 0, stream>>>(dst, E, bcnt, NB, NBH, W1, W2, w1t, w2t, g1, g2, N);
  k_bscan   <<<1, 1024, 0, stream>>>(bcnt, bofs, bcur, NB, E);
  k_binpass <<<(E+BIN_CHUNK-1)/BIN_CHUNK, 256, 0, stream>>>(src, dst, E, bcur, binned, NB);
  k_bscatter<<<NB, 256, 0, stream>>>(binned, bofs, csr, row_ofs, dinv, N, E, NB);

  k_gemm1   <<<(N+127)/128, 256, 0, stream>>>(x, w1t, dinv, g1, N);
  k_agg1g2  <<<(N+63)/64, 256, 0, stream>>>(g1, row_ofs, csr, dinv, b1, w2t, g2, N);
  k_agg2    <<<(N+31)/32, 256, 0, stream>>>(g2, row_ofs, csr, dinv, b2, out, N);
}